// Round 8
// baseline (188.413 us; speedup 1.0000x reference)
//
#include <hip/hip_runtime.h>

#define N_ATOMS 50000
#define N_PAIRS 1600000
#define FDIM 128

typedef short short8 __attribute__((ext_vector_type(8)));
typedef float floatx4 __attribute__((ext_vector_type(4)));

// fp32 -> bf16 round-to-nearest-even
__device__ inline ushort f2bf(float f) {
    union { float f; unsigned u; } v; v.f = f;
    unsigned lsb = (v.u >> 16) & 1u;
    return (ushort)((v.u + 0x7fffu + lsb) >> 16);
}
__device__ inline float bflo(unsigned u) { return __uint_as_float(u << 16); }
__device__ inline float bfhi(unsigned u) { return __uint_as_float(u & 0xffff0000u); }

#define GEMM_BLOCKS 782   // ceil(50000/64) rows
#define RP_BLOCKS   196   // ceil(50001/256)

// ---------------------------------------------------------------------------
// K1: fused (independent jobs by blockIdx):
//   [0, 782):    v = bf16(x @ W^T) via mfma_f32_16x16x32_bf16
//   [782, 978):  rowptr[i] = lower_bound(idx_i, i)
// ---------------------------------------------------------------------------
__global__ __launch_bounds__(256) void gemm_rowptr(const float* __restrict__ x,
                                                   const float* __restrict__ W,
                                                   const int* __restrict__ idx_i,
                                                   ushort* __restrict__ v,
                                                   int* __restrict__ rowptr) {
    const int t = threadIdx.x;
    if (blockIdx.x >= GEMM_BLOCKS) {
        const int i = (blockIdx.x - GEMM_BLOCKS) * 256 + t;
        if (i > N_ATOMS) return;
        int lo = 0, hi = N_PAIRS;
        while (lo < hi) {
            int mid = (lo + hi) >> 1;
            if (idx_i[mid] < i) lo = mid + 1; else hi = mid;
        }
        rowptr[i] = lo;
        return;
    }

    __shared__ ushort Wsh[128 * 136];
#pragma unroll
    for (int u = 0; u < 16; ++u) {
        int id = t + 256 * u;
        int f  = id >> 5;
        int k4 = (id & 31) * 4;
        const float4 w4 = *(const float4*)(W + f * FDIM + k4);
        ushort* d = &Wsh[f * 136 + k4];
        d[0] = f2bf(w4.x); d[1] = f2bf(w4.y); d[2] = f2bf(w4.z); d[3] = f2bf(w4.w);
    }
    __syncthreads();

    const int lane = t & 63, wv = t >> 6;
    const int mrow = lane & 15, q = lane >> 4;
    const int mw   = blockIdx.x * 64 + wv * 16;

    int row = mw + mrow;
    if (row >= N_ATOMS) row = N_ATOMS - 1;   // clamped reads; stores guarded
    const float* xr = x + (long)row * FDIM + 8 * q;

    short8 a[4];
#pragma unroll
    for (int kc = 0; kc < 4; ++kc) {
        const float4 lo4 = *(const float4*)(xr + 32 * kc);
        const float4 hi4 = *(const float4*)(xr + 32 * kc + 4);
        short8 af;
        af[0] = f2bf(lo4.x); af[1] = f2bf(lo4.y); af[2] = f2bf(lo4.z); af[3] = f2bf(lo4.w);
        af[4] = f2bf(hi4.x); af[5] = f2bf(hi4.y); af[6] = f2bf(hi4.z); af[7] = f2bf(hi4.w);
        a[kc] = af;
    }

    floatx4 acc[8];
#pragma unroll
    for (int f = 0; f < 8; ++f) acc[f] = (floatx4)(0.f);

#pragma unroll
    for (int f = 0; f < 8; ++f) {
        const ushort* wr = &Wsh[(16 * f + mrow) * 136 + 8 * q];
#pragma unroll
        for (int kc = 0; kc < 4; ++kc)
            acc[f] = __builtin_amdgcn_mfma_f32_16x16x32_bf16(a[kc], *(const short8*)(wr + 32 * kc), acc[f], 0, 0, 0);
    }

#pragma unroll
    for (int f = 0; f < 8; ++f) {
#pragma unroll
        for (int r = 0; r < 4; ++r) {
            const int orow = mw + 4 * q + r;
            if (orow < N_ATOMS)
                v[(long)orow * FDIM + 16 * f + mrow] = f2bf(acc[f][r]);
        }
    }
}

// ---------------------------------------------------------------------------
// K2: y[i,:] += sum_p alpha[p] * v[idx_j[p],:]  (fp32 atomics into zeroed y).
// TWO WAVES PER ATOM (100k waves — 2x TLP vs r5/r7): wave handles one half
// of the atom's pair range. Loop is r5's proven unroll-4 shape:
// lane = (g = pair-subgroup 0..3) x (c = 16B chunk 0..15); one dwordx4
// gathers FOUR rows (1 KB/instr). Epilogue: shfl-xor(16,32) reduce +
// 2 fp32 atomicAdds per lane (<=2 waves contend per row).
// ---------------------------------------------------------------------------
__global__ __launch_bounds__(256) void scatter_y(const ushort* __restrict__ v,
                                                 const float* __restrict__ alpha,
                                                 const int* __restrict__ idx_j,
                                                 const int* __restrict__ rowptr,
                                                 float* __restrict__ y) {
    const int lane = threadIdx.x & 63;
    const int wave = blockIdx.x * 4 + (threadIdx.x >> 6);   // [0, 100000)
    const int atom = wave >> 1;
    const int h    = wave & 1;
    if (atom >= N_ATOMS) return;
    const int g = lane >> 4;
    const int c = lane & 15;
    const char* vbase = (const char*)v + (c << 4);

    const int s0  = __builtin_amdgcn_readfirstlane(rowptr[atom]);
    const int e0  = __builtin_amdgcn_readfirstlane(rowptr[atom + 1]);
    const int mid = (s0 + e0) >> 1;
    const int s   = h ? mid : s0;
    const int e   = h ? e0 : mid;

    float acc[8];
#pragma unroll
    for (int k = 0; k < 8; ++k) acc[k] = 0.f;

#pragma unroll 4
    for (int p0 = s; p0 < e; p0 += 4) {
        const int  pp    = p0 + g;
        const bool valid = pp < e;
        const int  pc    = valid ? pp : s;          // s < e inside loop
        const int  j     = idx_j[pc];
        float      a     = alpha[pc];
        a = valid ? a : 0.f;
        const uint4 vv = *(const uint4*)(vbase + ((unsigned)j << 8));
        acc[0] += a * bflo(vv.x); acc[1] += a * bfhi(vv.x);
        acc[2] += a * bflo(vv.y); acc[3] += a * bfhi(vv.y);
        acc[4] += a * bflo(vv.z); acc[5] += a * bfhi(vv.z);
        acc[6] += a * bflo(vv.w); acc[7] += a * bfhi(vv.w);
    }

    // reduce the 4 pair-subgroups (lane bits 4,5)
#pragma unroll
    for (int k = 0; k < 8; ++k) {
        acc[k] += __shfl_xor(acc[k], 16);
        acc[k] += __shfl_xor(acc[k], 32);
    }

    // lane owns feats 8c+2g, 8c+2g+1 -> 512 B coalesced atomic adds
    const float e0f = (g & 1) ? acc[2] : acc[0];
    const float e1f = (g & 1) ? acc[3] : acc[1];
    const float f0f = (g & 1) ? acc[6] : acc[4];
    const float f1f = (g & 1) ? acc[7] : acc[5];
    const float o0 = (g & 2) ? f0f : e0f;
    const float o1 = (g & 2) ? f1f : e1f;
    float* yp = y + (long)atom * FDIM + 8 * c + 2 * g;
    atomicAdd(yp + 0, o0);
    atomicAdd(yp + 1, o1);
}

extern "C" void kernel_launch(void* const* d_in, const int* in_sizes, int n_in,
                              void* d_out, int out_size, void* d_ws, size_t ws_size,
                              hipStream_t stream) {
    const float* x     = (const float*)d_in[0];
    const float* alpha = (const float*)d_in[1];
    const int*   idx_i = (const int*)d_in[2];   // int32 per harness contract
    const int*   idx_j = (const int*)d_in[3];
    const float* W     = (const float*)d_in[4];
    float* y = (float*)d_out;

    // ws layout: v 12.8 MB | rowptr 200 KB
    ushort* v      = (ushort*)d_ws;
    int*    rowptr = (int*)((char*)d_ws + (size_t)N_ATOMS * FDIM * 2);

    hipMemsetAsync(d_out, 0, (size_t)out_size * sizeof(float), stream);
    gemm_rowptr<<<GEMM_BLOCKS + RP_BLOCKS, 256, 0, stream>>>(x, W, idx_i, v, rowptr);
    // 100000 waves = 25000 blocks of 4 waves (2 waves per atom)
    scatter_y<<<25000, 256, 0, stream>>>(v, alpha, idx_j, rowptr, y);
}

// Round 9
// 143.131 us; speedup vs baseline: 1.3164x; 1.3164x over previous
//
#include <hip/hip_runtime.h>

#define N_ATOMS 50000
#define N_PAIRS 1600000
#define FDIM 128

typedef short short8 __attribute__((ext_vector_type(8)));
typedef float floatx4 __attribute__((ext_vector_type(4)));

// fp32 -> bf16 round-to-nearest-even
__device__ inline ushort f2bf(float f) {
    union { float f; unsigned u; } v; v.f = f;
    unsigned lsb = (v.u >> 16) & 1u;
    return (ushort)((v.u + 0x7fffu + lsb) >> 16);
}
__device__ inline float bflo(unsigned u) { return __uint_as_float(u << 16); }
__device__ inline float bfhi(unsigned u) { return __uint_as_float(u & 0xffff0000u); }

#define GEMM_BLOCKS 782   // ceil(50000/64) rows
#define RP_BLOCKS   196   // ceil(50001/256)

// ---------------------------------------------------------------------------
// K1: fused (independent jobs by blockIdx):
//   [0, 782):    v = bf16(x @ W^T) via mfma_f32_16x16x32_bf16
//   [782, 978):  rowptr[i] = lower_bound(idx_i, i)
// ---------------------------------------------------------------------------
__global__ __launch_bounds__(256) void gemm_rowptr(const float* __restrict__ x,
                                                   const float* __restrict__ W,
                                                   const int* __restrict__ idx_i,
                                                   ushort* __restrict__ v,
                                                   int* __restrict__ rowptr) {
    const int t = threadIdx.x;
    if (blockIdx.x >= GEMM_BLOCKS) {
        const int i = (blockIdx.x - GEMM_BLOCKS) * 256 + t;
        if (i > N_ATOMS) return;
        int lo = 0, hi = N_PAIRS;
        while (lo < hi) {
            int mid = (lo + hi) >> 1;
            if (idx_i[mid] < i) lo = mid + 1; else hi = mid;
        }
        rowptr[i] = lo;
        return;
    }

    __shared__ ushort Wsh[128 * 136];
#pragma unroll
    for (int u = 0; u < 16; ++u) {
        int id = t + 256 * u;
        int f  = id >> 5;
        int k4 = (id & 31) * 4;
        const float4 w4 = *(const float4*)(W + f * FDIM + k4);
        ushort* d = &Wsh[f * 136 + k4];
        d[0] = f2bf(w4.x); d[1] = f2bf(w4.y); d[2] = f2bf(w4.z); d[3] = f2bf(w4.w);
    }
    __syncthreads();

    const int lane = t & 63, wv = t >> 6;
    const int mrow = lane & 15, q = lane >> 4;
    const int mw   = blockIdx.x * 64 + wv * 16;

    int row = mw + mrow;
    if (row >= N_ATOMS) row = N_ATOMS - 1;   // clamped reads; stores guarded
    const float* xr = x + (long)row * FDIM + 8 * q;

    short8 a[4];
#pragma unroll
    for (int kc = 0; kc < 4; ++kc) {
        const float4 lo4 = *(const float4*)(xr + 32 * kc);
        const float4 hi4 = *(const float4*)(xr + 32 * kc + 4);
        short8 af;
        af[0] = f2bf(lo4.x); af[1] = f2bf(lo4.y); af[2] = f2bf(lo4.z); af[3] = f2bf(lo4.w);
        af[4] = f2bf(hi4.x); af[5] = f2bf(hi4.y); af[6] = f2bf(hi4.z); af[7] = f2bf(hi4.w);
        a[kc] = af;
    }

    floatx4 acc[8];
#pragma unroll
    for (int f = 0; f < 8; ++f) acc[f] = (floatx4)(0.f);

#pragma unroll
    for (int f = 0; f < 8; ++f) {
        const ushort* wr = &Wsh[(16 * f + mrow) * 136 + 8 * q];
#pragma unroll
        for (int kc = 0; kc < 4; ++kc)
            acc[f] = __builtin_amdgcn_mfma_f32_16x16x32_bf16(a[kc], *(const short8*)(wr + 32 * kc), acc[f], 0, 0, 0);
    }

#pragma unroll
    for (int f = 0; f < 8; ++f) {
#pragma unroll
        for (int r = 0; r < 4; ++r) {
            const int orow = mw + 4 * q + r;
            if (orow < N_ATOMS)
                v[(long)orow * FDIM + 16 * f + mrow] = f2bf(acc[f][r]);
        }
    }
}

// ---------------------------------------------------------------------------
// K2: y[i,:] = sum_p alpha[p] * v[idx_j[p],:]  (fp32, direct, no atomics).
// ONE ATOM PER WAVE (50000 waves), r5's measured-fastest loop shape:
// lane = (g = pair-subgroup 0..3) x (c = 16B chunk 0..15); one dwordx4
// gathers FOUR rows (1 KB/instr); unroll 4. Epilogue: shfl-xor(16,32)
// reduce + 512 B coalesced float2 store.
// Measured floor evidence (r5-r8): FETCH pinned ~156 MB (8-XCD compulsory
// duplication of v + idx/alpha), ILP/TLP variants all >= 49 us.
// ---------------------------------------------------------------------------
__global__ __launch_bounds__(256) void scatter_y(const ushort* __restrict__ v,
                                                 const float* __restrict__ alpha,
                                                 const int* __restrict__ idx_j,
                                                 const int* __restrict__ rowptr,
                                                 float* __restrict__ y) {
    const int lane = threadIdx.x & 63;
    const int atom = blockIdx.x * 4 + (threadIdx.x >> 6);
    if (atom >= N_ATOMS) return;
    const int g = lane >> 4;
    const int c = lane & 15;
    const char* vbase = (const char*)v + (c << 4);

    const int start = __builtin_amdgcn_readfirstlane(rowptr[atom]);
    const int end   = __builtin_amdgcn_readfirstlane(rowptr[atom + 1]);

    float acc[8];
#pragma unroll
    for (int k = 0; k < 8; ++k) acc[k] = 0.f;

#pragma unroll 4
    for (int p0 = start; p0 < end; p0 += 4) {
        const int  pp    = p0 + g;
        const bool valid = pp < end;
        const int  pc    = valid ? pp : start;      // start < end inside loop
        const int  j     = idx_j[pc];
        float      a     = alpha[pc];
        a = valid ? a : 0.f;
        const uint4 vv = *(const uint4*)(vbase + ((unsigned)j << 8));
        acc[0] += a * bflo(vv.x); acc[1] += a * bfhi(vv.x);
        acc[2] += a * bflo(vv.y); acc[3] += a * bfhi(vv.y);
        acc[4] += a * bflo(vv.z); acc[5] += a * bfhi(vv.z);
        acc[6] += a * bflo(vv.w); acc[7] += a * bfhi(vv.w);
    }

    // reduce the 4 pair-subgroups (lane bits 4,5)
#pragma unroll
    for (int k = 0; k < 8; ++k) {
        acc[k] += __shfl_xor(acc[k], 16);
        acc[k] += __shfl_xor(acc[k], 32);
    }

    // lane stores feats 8c+2g, 8c+2g+1 -> 64 lanes x 8 B = 512 B coalesced
    const float e0 = (g & 1) ? acc[2] : acc[0];
    const float e1 = (g & 1) ? acc[3] : acc[1];
    const float f0 = (g & 1) ? acc[6] : acc[4];
    const float f1 = (g & 1) ? acc[7] : acc[5];
    float2 o;
    o.x = (g & 2) ? f0 : e0;
    o.y = (g & 2) ? f1 : e1;
    *(float2*)(y + (long)atom * FDIM + 8 * c + 2 * g) = o;
}

extern "C" void kernel_launch(void* const* d_in, const int* in_sizes, int n_in,
                              void* d_out, int out_size, void* d_ws, size_t ws_size,
                              hipStream_t stream) {
    const float* x     = (const float*)d_in[0];
    const float* alpha = (const float*)d_in[1];
    const int*   idx_i = (const int*)d_in[2];   // int32 per harness contract
    const int*   idx_j = (const int*)d_in[3];
    const float* W     = (const float*)d_in[4];
    float* y = (float*)d_out;

    // ws layout: v 12.8 MB | rowptr 200 KB
    ushort* v      = (ushort*)d_ws;
    int*    rowptr = (int*)((char*)d_ws + (size_t)N_ATOMS * FDIM * 2);

    gemm_rowptr<<<GEMM_BLOCKS + RP_BLOCKS, 256, 0, stream>>>(x, W, idx_i, v, rowptr);
    scatter_y<<<(N_ATOMS + 3) / 4, 256, 0, stream>>>(v, alpha, idx_j, rowptr, y);
}